// Round 3
// baseline (16.400 us; speedup 1.0000x reference)
//
#include <hip/hip_runtime.h>
#include <float.h>

typedef float f32x4 __attribute__((ext_vector_type(4)));

#define T_DIM 256
#define C_DIM 1024
#define B_DIM 16
#define G_CH  2                 // channels per wave
#define ROWB  1024              // bytes per level row (256 floats)
#define REGB  (5 * ROWB)        // one region: levels 1..5 (5 KB)

__device__ __forceinline__ float bpermf(int idx, float v) {
    return __int_as_float(__builtin_amdgcn_ds_bpermute(idx, __float_as_int(v)));
}
__device__ __forceinline__ f32x4 bperm4(int idx, f32x4 v) {
    f32x4 r;
    r.x = bpermf(idx, v.x); r.y = bpermf(idx, v.y);
    r.z = bpermf(idx, v.z); r.w = bpermf(idx, v.w);
    return r;
}
__device__ __forceinline__ f32x4 vmax4(f32x4 a, f32x4 b) {
    f32x4 r;
    r.x = fmaxf(a.x, b.x); r.y = fmaxf(a.y, b.y);
    r.z = fmaxf(a.z, b.z); r.w = fmaxf(a.w, b.w);
    return r;
}

// byte offset of float position p within a row, XOR-swizzled at 16B granularity
__device__ __forceinline__ int swz(int p)   { return (p << 2) ^ (((p >> 5) & 7) << 4); }
// same swizzle for a 16B block index (write addresses)
__device__ __forceinline__ int swz16(int b) { return (b << 4) ^ (((b >> 3) & 7) << 4); }

__global__ __launch_bounds__(256) void pool_kernel(
    const float* __restrict__ feat,
    const float* __restrict__ reg,
    float* __restrict__ out)
{
    __shared__ __align__(16) char lds[4 * REGB];   // 20 KB -> up to 8 blocks/CU
    const int tid  = threadIdx.x;
    const int wv   = tid >> 6;
    const int lane = tid & 63;
    const int i0   = lane << 2;                 // first t of this thread

    const int b    = blockIdx.x >> 7;           // grid = 16 * 128
    const int cblk = blockIdx.x & 127;
    const int c0   = (cblk << 3) + wv * G_CH;   // 8 channels per block

    const int wavebase = wv * REGB;
    const int wbyte = wavebase + swz16(lane);   // own table-write address
    const int idx1  = ((lane + 1) & 63) << 2;   // bpermute lane indices
    const int idx2  = ((lane + 2) & 63) << 2;
    const int idx4  = ((lane + 4) & 63) << 2;

    // Per-element query offsets (depend only on (b,t); reused per channel).
    // Wrap-tainted table entries (p + 2^k > 256) are provably never read.
    int qLa[4], qLb[4], qRa[4], qRb[4];
    bool zL[4], zR[4];
    {
        const float* rp = reg + ((size_t)b * T_DIM + i0) * 2;
        f32x4 ra = *(const f32x4*)rp;
        f32x4 rb = *(const f32x4*)(rp + 4);
        float r0v[4] = {ra.x, ra.z, rb.x, rb.z};   // reg[t][0]
        float r1v[4] = {ra.y, ra.w, rb.y, rb.w};   // reg[t][1]
        #pragma unroll
        for (int j = 0; j < 4; ++j) {
            int t = i0 + j;
            // left window [l, t+1), len 1..33
            int rl = (int)rintf(r0v[j]); rl = rl < 0 ? 0 : rl;
            int l = t - rl; l = l < 0 ? 0 : l;
            int lenL = t + 1 - l;
            int kL = 31 - __clz(lenL);
            int i2L = t + 1 - (1 << kL);
            // right window [t, re), len 1..32
            int rr = (int)rintf(r1v[j]); rr = rr < 1 ? 1 : rr;
            int re = t + rr; re = re > T_DIM ? T_DIM : re;
            int lenR = re - t;
            int kR = 31 - __clz(lenR);
            int i2R = re - (1 << kR);
            int rowL = (kL >= 1 ? kL - 1 : 0) * ROWB;   // level k stored at row k-1
            int rowR = (kR >= 1 ? kR - 1 : 0) * ROWB;
            qLa[j] = wavebase + rowL + swz(l);
            qLb[j] = wavebase + rowL + swz(i2L);
            qRa[j] = wavebase + rowR + swz(t);
            qRb[j] = wavebase + rowR + swz(i2R);
            zL[j] = (kL == 0);
            zR[j] = (kR == 0);
        }
    }

    // issue all channels' feat loads up front
    const size_t fbase = ((size_t)b * C_DIM + c0) * T_DIM + i0;
    f32x4 fv[G_CH];
    #pragma unroll
    for (int g = 0; g < G_CH; ++g)
        fv[g] = *(const f32x4*)(feat + fbase + (size_t)g * T_DIM);

    // No fences anywhere: bperms touch no LDS storage (free to pipeline);
    // table write->read and read->next-write ordering is preserved by LLVM
    // (may-alias) and executed in order by the per-wave DS pipe (R1/R2-proven).
    #pragma unroll
    for (int g = 0; g < G_CH; ++g) {
        f32x4 f = fv[g];

        // build levels 1..5 fully in registers
        float e1 = bpermf(idx1, f.x);
        f32x4 v1;
        v1.x = fmaxf(f.x, f.y); v1.y = fmaxf(f.y, f.z);
        v1.z = fmaxf(f.z, f.w); v1.w = fmaxf(f.w, e1);
        float a0 = bpermf(idx1, v1.x), a1 = bpermf(idx1, v1.y);
        f32x4 v2;
        v2.x = fmaxf(v1.x, v1.z); v2.y = fmaxf(v1.y, v1.w);
        v2.z = fmaxf(v1.z, a0);   v2.w = fmaxf(v1.w, a1);
        f32x4 v3 = vmax4(v2, bperm4(idx1, v2));
        f32x4 v4 = vmax4(v3, bperm4(idx2, v3));
        f32x4 v5 = vmax4(v4, bperm4(idx4, v4));

        // one-shot table write (5 x ds_write_b128, fire-and-forget)
        *(f32x4*)(lds + wbyte + 0 * ROWB) = v1;
        *(f32x4*)(lds + wbyte + 1 * ROWB) = v2;
        *(f32x4*)(lds + wbyte + 2 * ROWB) = v3;
        *(f32x4*)(lds + wbyte + 3 * ROWB) = v4;
        *(f32x4*)(lds + wbyte + 4 * ROWB) = v5;

        // queries: 12 scattered b32 reads (k==0 served from registers)
        f32x4 res;
        #pragma unroll
        for (int j = 0; j < 4; ++j) {
            float la = *(const float*)(lds + qLa[j]);
            float lb = *(const float*)(lds + qLb[j]);
            float ra = *(const float*)(lds + qRa[j]);
            float rb = *(const float*)(lds + qRb[j]);
            float fj = (j == 0) ? f.x : (j == 1) ? f.y : (j == 2) ? f.z : f.w;
            float left  = zL[j] ? fj : fmaxf(la, lb);
            float right = zR[j] ? fj : fmaxf(ra, rb);
            float v = left + right;
            if (j == 0) res.x = v;
            else if (j == 1) res.y = v;
            else if (j == 2) res.z = v;
            else res.w = v;
        }
        *(f32x4*)(out + fbase + (size_t)g * T_DIM) = res;
    }
}

extern "C" void kernel_launch(void* const* d_in, const int* in_sizes, int n_in,
                              void* d_out, int out_size, void* d_ws, size_t ws_size,
                              hipStream_t stream) {
    const float* feat = (const float*)d_in[0];
    const float* reg  = (const float*)d_in[1];
    float* out = (float*)d_out;
    // grid: B(16) * C/(4 waves * G_CH) = 16 * 128 = 2048 blocks
    pool_kernel<<<dim3(B_DIM * (C_DIM / (4 * G_CH))), 256, 0, stream>>>(feat, reg, out);
}

// Round 4
// 14.764 us; speedup vs baseline: 1.1108x; 1.1108x over previous
//
#include <hip/hip_runtime.h>
#include <float.h>

typedef float f32x4 __attribute__((ext_vector_type(4)));

#define T_DIM 256
#define C_DIM 1024
#define B_DIM 16
#define ROW   272              // 256 + 16 pad words (-FLT_MAX)
#define ROWB  (ROW * 4)        // row stride in bytes
#define NLEV  6                // levels 0..5 cover window len <= 33
#define WAVE_F (NLEV * ROW)    // floats per wave-private LDS region
#define G_CH  2                // channels per wave (sequential)

// Compiler-ordering fence for wave-synchronous LDS use (each wave owns a
// private LDS region; HW executes a wave's DS ops in order, we only need to
// stop the compiler from moving the cross-lane read above the write).
__device__ __forceinline__ void wave_fence() {
    __builtin_amdgcn_fence(__ATOMIC_ACQ_REL, "wavefront");
    __builtin_amdgcn_wave_barrier();
}

__device__ __forceinline__ f32x4 vmax4(f32x4 a, f32x4 b) {
    f32x4 r;
    r.x = fmaxf(a.x, b.x); r.y = fmaxf(a.y, b.y);
    r.z = fmaxf(a.z, b.z); r.w = fmaxf(a.w, b.w);
    return r;
}

__global__ __launch_bounds__(256) void pool_kernel(
    const float* __restrict__ feat,
    const float* __restrict__ reg,
    float* __restrict__ out)
{
    __shared__ float lds[4 * WAVE_F];
    const int tid  = threadIdx.x;
    const int wv   = tid >> 6;
    const int lane = tid & 63;
    const int i0   = lane << 2;            // this thread's first t

    const int b    = blockIdx.x >> 7;      // grid = 16 * 128
    const int cblk = blockIdx.x & 127;
    const int c0   = (cblk << 3) + wv * G_CH;

    float* __restrict__ L = &lds[wv * WAVE_F];
    char*  __restrict__ Lb = (char*)L;

    // init pad words of this wave's region to -FLT_MAX (96 words)
    {
        int idx = lane;
        if (idx < NLEV * 16) {
            int row = idx >> 4, w = idx & 15;
            L[row * ROW + 256 + w] = -FLT_MAX;
        }
        idx = lane + 64;
        if (idx < NLEV * 16) {
            int row = idx >> 4, w = idx & 15;
            L[row * ROW + 256 + w] = -FLT_MAX;
        }
    }

    // Per-element query byte-offsets (depend only on (b,t); reused per channel)
    int offLa[4], offLb[4], offRa[4], offRb[4];
    {
        const float* rp = reg + ((size_t)b * T_DIM + i0) * 2;
        f32x4 ra = *(const f32x4*)rp;
        f32x4 rb = *(const f32x4*)(rp + 4);
        float r0v[4] = {ra.x, ra.z, rb.x, rb.z};   // reg[t][0]
        float r1v[4] = {ra.y, ra.w, rb.y, rb.w};   // reg[t][1]
        #pragma unroll
        for (int j = 0; j < 4; ++j) {
            int t = i0 + j;
            // left window [l, t+1)
            int rl = (int)rintf(r0v[j]); rl = rl < 0 ? 0 : rl;
            int l = t - rl; l = l < 0 ? 0 : l;
            int lenL = t + 1 - l;                  // 1..33
            int kL = 31 - __clz(lenL);
            int i2L = t + 1 - (1 << kL);
            // right window [t, re)
            int rr = (int)rintf(r1v[j]); rr = rr < 1 ? 1 : rr;
            int re = t + rr; re = re > T_DIM ? T_DIM : re;
            int lenR = re - t;                     // 1..32
            int kR = 31 - __clz(lenR);
            int i2R = re - (1 << kR);
            offLa[j] = kL * ROWB + (l   << 2);
            offLb[j] = kL * ROWB + (i2L << 2);
            offRa[j] = kR * ROWB + (t   << 2);
            offRb[j] = kR * ROWB + (i2R << 2);
        }
    }

    // issue both channels' feat loads up front
    const size_t fbase = ((size_t)b * C_DIM + c0) * T_DIM + i0;
    f32x4 fv0 = *(const f32x4*)(feat + fbase);
    f32x4 fv1 = *(const f32x4*)(feat + fbase + T_DIM);

    wave_fence();   // pad writes visible before any build reads

    #pragma unroll
    for (int g = 0; g < G_CH; ++g) {
        f32x4 f = (g == 0) ? fv0 : fv1;
        const int bo = i0 << 2;  // byte offset of own block within a row

        // level 0
        *(f32x4*)(Lb + bo) = f;
        wave_fence();
        // level 1 (shift 1)
        f32x4 n0 = *(const f32x4*)(Lb + bo + 16);
        f32x4 v1;
        v1.x = fmaxf(f.x, f.y); v1.y = fmaxf(f.y, f.z);
        v1.z = fmaxf(f.z, f.w); v1.w = fmaxf(f.w, n0.x);
        *(f32x4*)(Lb + ROWB + bo) = v1;
        wave_fence();
        // level 2 (shift 2)
        f32x4 n1 = *(const f32x4*)(Lb + ROWB + bo + 16);
        f32x4 v2;
        v2.x = fmaxf(v1.x, v1.z); v2.y = fmaxf(v1.y, v1.w);
        v2.z = fmaxf(v1.z, n1.x); v2.w = fmaxf(v1.w, n1.y);
        *(f32x4*)(Lb + 2 * ROWB + bo) = v2;
        wave_fence();
        // level 3 (shift 4)
        f32x4 n2 = *(const f32x4*)(Lb + 2 * ROWB + bo + 16);
        f32x4 v3 = vmax4(v2, n2);
        *(f32x4*)(Lb + 3 * ROWB + bo) = v3;
        wave_fence();
        // level 4 (shift 8)
        f32x4 n3 = *(const f32x4*)(Lb + 3 * ROWB + bo + 32);
        f32x4 v4 = vmax4(v3, n3);
        *(f32x4*)(Lb + 4 * ROWB + bo) = v4;
        wave_fence();
        // level 5 (shift 16)
        f32x4 n4 = *(const f32x4*)(Lb + 4 * ROWB + bo + 64);
        f32x4 v5 = vmax4(v4, n4);
        *(f32x4*)(Lb + 5 * ROWB + bo) = v5;
        wave_fence();

        // queries: 4 scattered ds_read_b32 per element
        f32x4 res;
        #pragma unroll
        for (int j = 0; j < 4; ++j) {
            float la  = *(const float*)(Lb + offLa[j]);
            float lb2 = *(const float*)(Lb + offLb[j]);
            float ra2 = *(const float*)(Lb + offRa[j]);
            float rb2 = *(const float*)(Lb + offRb[j]);
            float v = fmaxf(la, lb2) + fmaxf(ra2, rb2);
            if (j == 0) res.x = v;
            else if (j == 1) res.y = v;
            else if (j == 2) res.z = v;
            else res.w = v;
        }
        *(f32x4*)(out + fbase + (size_t)g * T_DIM) = res;
        wave_fence();   // queries done before next channel overwrites tables
    }
}

extern "C" void kernel_launch(void* const* d_in, const int* in_sizes, int n_in,
                              void* d_out, int out_size, void* d_ws, size_t ws_size,
                              hipStream_t stream) {
    const float* feat = (const float*)d_in[0];
    const float* reg  = (const float*)d_in[1];
    float* out = (float*)d_out;
    // grid: B(16) * C/(4 waves * G_CH channels) = 16 * 128 = 2048 blocks
    pool_kernel<<<dim3(B_DIM * (C_DIM / (4 * G_CH))), 256, 0, stream>>>(feat, reg, out);
}